// Round 7
// baseline (3613.835 us; speedup 1.0000x reference)
//
#include <hip/hip_runtime.h>
#include <math.h>

#define BN_EPS 1e-3f

typedef unsigned short ushort;
typedef unsigned int uint;
typedef __attribute__((ext_vector_type(8))) short bf16x8;
typedef __attribute__((ext_vector_type(4))) float f32x4;

__device__ __forceinline__ float hsig(float x) {
    return fminf(fmaxf(0.2f * x + 0.5f, 0.f), 1.f);
}
__device__ __forceinline__ ushort f2bf(float f) {
    uint u = __float_as_uint(f);
    u += 0x7fffu + ((u >> 16) & 1u);   // RNE
    return (ushort)(u >> 16);
}

// ---------------------------------------------------------------------------
// pack_w: fp32 weights [3,Cin,4F]+[3,F,4F] -> bf16 fragment-order, FT=32.
// wp[nblk][step][slot][8], slot = (gate*2+wn)*64 + q*16 + r,
// element = W[k = step*32 + q*8 + j][n = gate*F + nblk*32 + wn*16 + r].
// steps [0,S0) from Wx (k < 3*Cin valid, else 0), rest from Wh.
// grid: (F/32, S), block 256.
// ---------------------------------------------------------------------------
__global__ __launch_bounds__(256)
void pack_w(const float* __restrict__ Wx, int Cin,
            const float* __restrict__ Wh, int F,
            uint4* __restrict__ wp, int S0, int S)
{
    __shared__ ushort Wt[32][136];
    const int nblk = blockIdx.x, step = blockIdx.y;
    const int tid = threadIdx.x;
    const int N4 = 4 * F;

    for (int idx = tid; idx < 32 * 128; idx += 256) {
        int kk = idx >> 7, c = idx & 127;
        int gate = c >> 5, fl = c & 31;
        int n = gate * F + nblk * 32 + fl;
        float v = 0.f;
        if (step < S0) {
            int ka = step * 32 + kk;
            if (ka < 3 * Cin) v = Wx[(long)ka * N4 + n];
        } else {
            int ka = (step - S0) * 32 + kk;
            v = Wh[(long)ka * N4 + n];
        }
        Wt[kk][c] = f2bf(v);
    }
    __syncthreads();

    for (int s = tid; s < 512; s += 256) {
        int colgrp = s >> 6, qq = (s >> 4) & 3, rr = s & 15;
        int gate = colgrp >> 1, wn = colgrp & 1;
        int c = gate * 32 + wn * 16 + rr;
        ushort tmp[8];
#pragma unroll
        for (int j = 0; j < 8; ++j) tmp[j] = Wt[qq * 8 + j][c];
        wp[(long)(nblk * S + step) * 512 + s] = *(const uint4*)tmp;
    }
}

// ---------------------------------------------------------------------------
// One 64(l) x 32(f) gate tile for one timestep of one layer (device fn).
// WM=2, WN=2, MT=2; 128 cols = 4 gates x 32 features; lane's 4 n-frags are
// the 4 gates of ONE feature -> thread-local gate combine. LDS frag-order,
// conflict-free ds_read_b128. Layer params are compile-time.
// ---------------------------------------------------------------------------
template<int F, int C0, int S0, int S, int NFL2, bool CIN1>
__device__ void gate_tile(const void* a0, long a0_bs,
                          const ushort* h_old, ushort* h_new,
                          const uint4* wp, const float* bias, float* c_state,
                          void* bn_out, long bn_bs, int bnf32,
                          const float* bng, const float* bnb,
                          const float* bnm, const float* bnv,
                          int L, int tile,
                          ushort (&As)[3][2048], ushort (&Bs)[3][4096])
{
    constexpr int MT = 2;
    constexpr int ASLOTS = 256;
    constexpr int BSLOTS = 512;
    constexpr int c0sh = (C0 >= 2) ? (31 - __builtin_clz((unsigned)C0)) : 0;
    constexpr int cFsh = 31 - __builtin_clz((unsigned)F);

    const int fblk = tile & ((1 << NFL2) - 1);
    const int rest = tile >> NFL2;
    const int lblk = rest & 1;
    const int b = rest >> 1;

    const int tid = threadIdx.x;
    const int lane = tid & 63;
    const int wave = tid >> 6;
    const int wn = wave & 1, wm = wave >> 1;
    const int q = lane >> 4, r = lane & 15;
    const int f0 = fblk * 32;
    const int l0 = lblk * 64;

    f32x4 acc[MT][4];
#pragma unroll
    for (int mt = 0; mt < MT; ++mt)
#pragma unroll
        for (int g = 0; g < 4; ++g) acc[mt][g] = (f32x4)(0.f);

    for (int r0 = 0; r0 < S; r0 += 3) {
        const int ns = (S - r0 < 3) ? (S - r0) : 3;
        __syncthreads();
        for (int ss = 0; ss < ns; ++ss) {
            const int step = r0 + ss;
            // ---- B stage: coalesced 16B copies from packed weights ----
            for (int s = tid; s < BSLOTS; s += 256)
                ((uint4*)Bs[ss])[s] = wp[((long)fblk * S + step) * BSLOTS + s];
            // ---- A stage: im2col into fragment order ----
            for (int s = tid; s < ASLOTS; s += 256) {
                const int mtile = s >> 6, within = s & 63;
                const int qq = within >> 4, rr = within & 15;
                const int row = mtile * 16 + rr;
                if (CIN1 && step < S0) {
                    const float* xb = (const float*)a0 + (long)b * a0_bs;
#pragma unroll
                    for (int j = 0; j < 8; ++j) {
                        ushort v = 0;
                        int k = qq * 8 + j;
                        if (k < 3) {
                            int l = l0 + row - 1 + k;
                            if (l >= 0 && l < L) v = f2bf(xb[l]);
                        }
                        As[ss][s * 8 + j] = v;
                    }
                } else {
                    const ushort* Ab;
                    int local, csh;
                    if (step < S0) {
                        Ab = (const ushort*)a0 + (long)b * a0_bs;
                        local = step; csh = c0sh;
                    } else {
                        Ab = h_old + ((long)b * L << cFsh);
                        local = step - S0; csh = cFsh;
                    }
                    const int kb = local * 32;
                    const int tap = kb >> csh;
                    const int ch0 = kb & ((1 << csh) - 1);
                    const int l = l0 + row - 1 + tap;
                    uint4 val = {0u, 0u, 0u, 0u};
                    if (l >= 0 && l < L)
                        val = *(const uint4*)&Ab[((long)l << csh) + ch0 + qq * 8];
                    ((uint4*)As[ss])[s] = val;
                }
            }
        }
        __syncthreads();
        for (int ss = 0; ss < ns; ++ss) {
            bf16x8 af[MT], bfr[4];
#pragma unroll
            for (int mt = 0; mt < MT; ++mt)
                af[mt] = *(const bf16x8*)&As[ss][((wm * MT + mt) * 64 + lane) * 8];
#pragma unroll
            for (int g = 0; g < 4; ++g)
                bfr[g] = *(const bf16x8*)&Bs[ss][((g * 2 + wn) * 64 + lane) * 8];
#pragma unroll
            for (int mt = 0; mt < MT; ++mt)
#pragma unroll
                for (int g = 0; g < 4; ++g)
                    acc[mt][g] = __builtin_amdgcn_mfma_f32_16x16x32_bf16(
                        af[mt], bfr[g], acc[mt][g], 0, 0, 0);
        }
    }

    // ---- epilogue: bias, gates, state update, optional BN ----
    const int f = f0 + wn * 16 + r;
    const float b_i = bias[f], b_f = bias[F + f];
    const float b_c = bias[2 * F + f], b_o = bias[3 * F + f];
    float sc = 0.f, sh = 0.f;
    if (bn_out) {
        sc = bng[f] * rsqrtf(bnv[f] + BN_EPS);
        sh = bnb[f] - bnm[f] * sc;
    }
#pragma unroll
    for (int mt = 0; mt < MT; ++mt) {
#pragma unroll
        for (int reg = 0; reg < 4; ++reg) {
            const int l = l0 + (wm * MT + mt) * 16 + q * 4 + reg;
            const long idx = (((long)b * L + l) << cFsh) + f;
            float gi = acc[mt][0][reg] + b_i;
            float gf = acc[mt][1][reg] + b_f;
            float gc = acc[mt][2][reg] + b_c;
            float go = acc[mt][3][reg] + b_o;
            float cold = c_state[idx];
            float cn = hsig(gf) * cold + hsig(gi) * fmaxf(gc, 0.f);
            float hn = hsig(go) * fmaxf(cn, 0.f);
            c_state[idx] = cn;
            h_new[idx] = f2bf(hn);
            if (bn_out) {
                float bv = hn * sc + sh;
                if (bnf32)
                    ((float*)bn_out)[(long)b * bn_bs + ((long)l << cFsh) + f] = bv;
                else
                    ((ushort*)bn_out)[(long)b * bn_bs + ((long)l << cFsh) + f] = f2bf(bv);
            }
        }
    }
}

// ---------------------------------------------------------------------------
// Hand-rolled grid barrier (no cooperative API). Monotonic arrival counters
// (16, spread 64B apart -> parallel at the coherence point; never reset -> no
// ABA), generation word bumped by block 0. Device-scope atomics + explicit
// __threadfence on both sides handle cross-XCD L2 non-coherence:
// release = wb dirty L2 to IC before arrival; acquire = invalidate L1/L2
// after the spin so phase-(d+1) reads refetch fresh lines.
// bar[i*16] i<16: counters; bar[256]: generation. Zeroed host-side per call.
// ---------------------------------------------------------------------------
__device__ __forceinline__ void grid_barrier(uint* bar, uint nb, uint phase)
{
    __syncthreads();   // all waves drain vm before s_barrier -> stores in L2
    if (threadIdx.x == 0) {
        __threadfence();   // release: write back L2 so data reaches IC
        __hip_atomic_fetch_add(&bar[(blockIdx.x & 15) * 16], 1u,
                               __ATOMIC_RELEASE, __HIP_MEMORY_SCOPE_AGENT);
        if (blockIdx.x == 0) {
            for (;;) {
                uint s = 0;
#pragma unroll
                for (int i = 0; i < 16; ++i)
                    s += __hip_atomic_load(&bar[i * 16], __ATOMIC_RELAXED,
                                           __HIP_MEMORY_SCOPE_AGENT);
                if (s >= nb * phase) break;
                __builtin_amdgcn_s_sleep(1);
            }
            __hip_atomic_store(&bar[256], phase, __ATOMIC_RELEASE,
                               __HIP_MEMORY_SCOPE_AGENT);
        } else {
            while (__hip_atomic_load(&bar[256], __ATOMIC_RELAXED,
                                     __HIP_MEMORY_SCOPE_AGENT) < phase)
                __builtin_amdgcn_s_sleep(1);
        }
        __threadfence();   // acquire: invalidate stale L1/L2 lines
    }
    __syncthreads();
}

// ---------------------------------------------------------------------------
// Persistent ConvLSTM, REGULAR launch, 768 blocks = exactly 3 blocks/CU.
// Static co-residency guarantee: LDS 36.9 KB -> 4 blocks/CU; launch_bounds
// (256,3) caps VGPRs for >=3 waves/EU -> >=3 blocks/CU; 768 = 3 x 256 CUs.
// Block map: [0,512) L3; [512,768) L2, first 128 of those also L1.
// Phase d: L1@t=d, L2@t=d-1, L3@t=d-2; hand-rolled barrier between phases.
// ---------------------------------------------------------------------------
struct PCfg {
    const float* x;
    const uint4 *wp1, *wp2, *wp3;
    const float *b1, *b2, *b3;
    ushort *h1seq, *h2seq;
    ushort *h1a, *h1b, *h2a, *h2b, *h3a, *h3b;
    float *c1s, *c2s, *c3s;
    float *h3bn;
    const float *g1, *be1, *m1, *v1;
    const float *g2, *be2, *m2, *v2;
    const float *g3, *be3, *m3, *v3;
    int T, L;
};

__global__ __launch_bounds__(256, 3)
void convlstm_persist(PCfg p, uint* bar)
{
    __shared__ ushort As[3][2048];
    __shared__ ushort Bs[3][4096];
    const int bid = blockIdx.x;
    const int T = p.T, L = p.L;

    for (int d = 0; d < T + 2; ++d) {
        if (bid < 512) {
            int t = d - 2;
            if (t >= 0 && t < T)
                gate_tile<256, 128, 12, 36, 3, false>(
                    p.h2seq + (long)t * L * 128, (long)T * L * 128,
                    (t & 1) ? p.h3b : p.h3a, (t & 1) ? p.h3a : p.h3b,
                    p.wp3, p.b3, p.c3s,
                    (t == T - 1) ? (void*)p.h3bn : nullptr, (long)L * 256, 1,
                    p.g3, p.be3, p.m3, p.v3, L, bid, As, Bs);
        } else {
            int t2 = d - 1;
            if (t2 >= 0 && t2 < T)
                gate_tile<128, 64, 6, 18, 2, false>(
                    p.h1seq + (long)t2 * L * 64, (long)T * L * 64,
                    (t2 & 1) ? p.h2b : p.h2a, (t2 & 1) ? p.h2a : p.h2b,
                    p.wp2, p.b2, p.c2s,
                    p.h2seq + (long)t2 * L * 128, (long)T * L * 128, 0,
                    p.g2, p.be2, p.m2, p.v2, L, bid - 512, As, Bs);
            int t1 = d;
            if (bid - 512 < 128 && t1 < T)
                gate_tile<64, 1, 1, 7, 1, true>(
                    p.x + (long)t1 * L, (long)T * L,
                    (t1 & 1) ? p.h1b : p.h1a, (t1 & 1) ? p.h1a : p.h1b,
                    p.wp1, p.b1, p.c1s,
                    p.h1seq + (long)t1 * L * 64, (long)T * L * 64, 0,
                    p.g1, p.be1, p.m1, p.v1, L, bid - 512, As, Bs);
        }
        if (d < T + 1) grid_barrier(bar, 768u, (uint)(d + 1));
    }
}

// ---------------------------------------------------------------------------
// dense_partial v4: n-tile=128, KT=256, grid (N/128, K/256) = (8,128) = 1024
// blocks (4/CU). Thread = 4n x 4m; unroll 8 -> 8 independent float4 W loads.
// ---------------------------------------------------------------------------
__global__ __launch_bounds__(256)
void dense_partial(const float* __restrict__ A,   // [32, K]
                   const float* __restrict__ Wt,  // [K, N]
                   float* __restrict__ partials,  // [nK, 32, N]
                   int K, int N)
{
    __shared__ __align__(16) float A_s[256 * 32];   // [k][m], 32 KB
    const int n0 = blockIdx.x * 128;
    const int k0 = blockIdx.y * 256;
    const int tid = threadIdx.x;

    for (int idx = tid; idx < 256 * 32; idx += 256) {
        int k = idx >> 5, m = idx & 31;
        A_s[idx] = A[(long)m * K + k0 + k];
    }
    __syncthreads();

    const int nq = (tid & 31) * 4;
    const int mg = tid >> 5;          // 8 m-groups x 4 rows
    f32x4 acc[4];
#pragma unroll
    for (int i = 0; i < 4; ++i) acc[i] = (f32x4)(0.f);

#pragma unroll 8
    for (int k = 0; k < 256; ++k) {
        const float4 w4 = *(const float4*)&Wt[(long)(k0 + k) * N + n0 + nq];
        const float* ap = &A_s[k * 32 + mg * 4];
#pragma unroll
        for (int mm = 0; mm < 4; ++mm) {
            float a = ap[mm];
            acc[mm][0] += a * w4.x;
            acc[mm][1] += a * w4.y;
            acc[mm][2] += a * w4.z;
            acc[mm][3] += a * w4.w;
        }
    }

#pragma unroll
    for (int mm = 0; mm < 4; ++mm)
        *(f32x4*)&partials[((long)blockIdx.y * 32 + mg * 4 + mm) * N + n0 + nq] = acc[mm];
}

__global__ __launch_bounds__(256)
void dense_reduce_relu(const float* __restrict__ partials,
                       const float* __restrict__ bias,
                       float* __restrict__ out, int N, int nK)
{
    int idx = blockIdx.x * 256 + threadIdx.x;
    int m = idx / N, n = idx % N;
    float s = bias[n];
    for (int j = 0; j < nK; ++j) s += partials[((long)j * 32 + m) * N + n];
    out[idx] = fmaxf(s, 0.f);
}

// D2: K=1024 fits in LDS once.
__global__ __launch_bounds__(256)
void dense_relu(const float* __restrict__ A, const float* __restrict__ Wt,
                const float* __restrict__ bias, float* __restrict__ out,
                int K, int N)
{
    __shared__ float A_s[1024];
    int n = blockIdx.x * 256 + threadIdx.x;
    int m = blockIdx.y;
    for (int k = threadIdx.x; k < K; k += 256) A_s[k] = A[(long)m * K + k];
    __syncthreads();
    float acc = 0.f;
#pragma unroll 8
    for (int k = 0; k < K; ++k)
        acc += A_s[k] * Wt[(long)k * N + n];
    out[(long)m * N + n] = fmaxf(acc + bias[n], 0.f);
}

__global__ __launch_bounds__(64)
void dense_softmax(const float* __restrict__ A, const float* __restrict__ W,
                   const float* __restrict__ bias, float* __restrict__ out)
{
    int b = blockIdx.x;
    int tid = threadIdx.x;
    __shared__ float logits[5];

    float part[5] = {0.f, 0.f, 0.f, 0.f, 0.f};
    for (int k = tid; k < 512; k += 64) {
        float a = A[b * 512 + k];
#pragma unroll
        for (int j = 0; j < 5; ++j) part[j] += a * W[k * 5 + j];
    }
#pragma unroll
    for (int j = 0; j < 5; ++j) {
        float v = part[j];
        for (int off = 32; off; off >>= 1) v += __shfl_down(v, off);
        if (tid == 0) logits[j] = v + bias[j];
    }
    __syncthreads();
    if (tid == 0) {
        float mx = logits[0];
        for (int j = 1; j < 5; ++j) mx = fmaxf(mx, logits[j]);
        float s = 0.f, e[5];
        for (int j = 0; j < 5; ++j) { e[j] = expf(logits[j] - mx); s += e[j]; }
        for (int j = 0; j < 5; ++j) out[b * 5 + j] = e[j] / s;
    }
}

extern "C" void kernel_launch(void* const* d_in, const int* in_sizes, int n_in,
                              void* d_out, int out_size, void* d_ws, size_t ws_size,
                              hipStream_t stream)
{
    const int B = 32, T = 32, L = 128;
    const int F1 = 64, F2 = 128, F3 = 256;

    const float* x   = (const float*)d_in[0];
    const float* Wx1 = (const float*)d_in[1];
    const float* Wh1 = (const float*)d_in[2];
    const float* b1  = (const float*)d_in[3];
    const float* Wx2 = (const float*)d_in[4];
    const float* Wh2 = (const float*)d_in[5];
    const float* b2  = (const float*)d_in[6];
    const float* Wx3 = (const float*)d_in[7];
    const float* Wh3 = (const float*)d_in[8];
    const float* b3  = (const float*)d_in[9];
    const float* g1  = (const float*)d_in[10];
    const float* be1 = (const float*)d_in[11];
    const float* m1  = (const float*)d_in[12];
    const float* v1  = (const float*)d_in[13];
    const float* g2  = (const float*)d_in[14];
    const float* be2 = (const float*)d_in[15];
    const float* m2  = (const float*)d_in[16];
    const float* v2  = (const float*)d_in[17];
    const float* g3  = (const float*)d_in[18];
    const float* be3 = (const float*)d_in[19];
    const float* m3  = (const float*)d_in[20];
    const float* v3  = (const float*)d_in[21];
    const float* D1  = (const float*)d_in[22];
    const float* db1 = (const float*)d_in[23];
    const float* D2  = (const float*)d_in[24];
    const float* db2 = (const float*)d_in[25];
    const float* D3  = (const float*)d_in[26];
    const float* db3 = (const float*)d_in[27];
    (void)in_sizes; (void)n_in; (void)out_size; (void)ws_size;

    // ---- workspace layout ----
    char* p = (char*)d_ws;
    ushort* h1seq = (ushort*)p; p += (size_t)B * T * L * F1 * 2;       // 16.8 MB
    ushort* h2seq = (ushort*)p; p += (size_t)B * T * L * F2 * 2;       // 33.6 MB
    ushort* h1a = (ushort*)p; p += (size_t)B * L * F1 * 2;
    ushort* h1b = (ushort*)p; p += (size_t)B * L * F1 * 2;
    ushort* h2a = (ushort*)p; p += (size_t)B * L * F2 * 2;
    ushort* h2b = (ushort*)p; p += (size_t)B * L * F2 * 2;
    ushort* h3a = (ushort*)p; p += (size_t)B * L * F3 * 2;
    ushort* h3b = (ushort*)p; p += (size_t)B * L * F3 * 2;
    float*  c1s = (float*)p; p += (size_t)B * L * F1 * 4;
    float*  c2s = (float*)p; p += (size_t)B * L * F2 * 4;
    float*  c3s = (float*)p; p += (size_t)B * L * F3 * 4;
    float*  h3bn = (float*)p; p += (size_t)B * L * F3 * 4;
    uint4*  wp1 = (uint4*)p; p += (size_t)2 * 7 * 512 * 16;
    uint4*  wp2 = (uint4*)p; p += (size_t)4 * 18 * 512 * 16;
    uint4*  wp3 = (uint4*)p; p += (size_t)8 * 36 * 512 * 16;
    float*  a1 = (float*)p; p += (size_t)B * 1024 * 4;
    float*  a2 = (float*)p; p += (size_t)B * 512 * 4;
    uint*   bar = (uint*)p; p += 2048;            // barrier counters + gen
    float* partials = (float*)h2seq;   // 128*32*1024*4 = 16.8 MB, dead-slab alias

    // ---- pack weights ----
    pack_w<<<dim3(2, 7), 256, 0, stream>>>(Wx1, 1, Wh1, F1, wp1, 1, 7);
    pack_w<<<dim3(4, 18), 256, 0, stream>>>(Wx2, F1, Wh2, F2, wp2, 6, 18);
    pack_w<<<dim3(8, 36), 256, 0, stream>>>(Wx3, F2, Wh3, F3, wp3, 12, 36);

    // ---- zero initial states + barrier ----
    hipMemsetAsync(h1a, 0, (size_t)B * L * F1 * 2, stream);
    hipMemsetAsync(h2a, 0, (size_t)B * L * F2 * 2, stream);
    hipMemsetAsync(h3a, 0, (size_t)B * L * F3 * 2, stream);
    hipMemsetAsync(c1s, 0, (size_t)B * L * F1 * 4, stream);
    hipMemsetAsync(c2s, 0, (size_t)B * L * F2 * 4, stream);
    hipMemsetAsync(c3s, 0, (size_t)B * L * F3 * 4, stream);
    hipMemsetAsync(bar, 0, 2048, stream);

    // ---- persistent ConvLSTM: 768 blocks (3/CU static), hand-rolled barrier
    PCfg pc;
    pc.x = x;
    pc.wp1 = wp1; pc.wp2 = wp2; pc.wp3 = wp3;
    pc.b1 = b1; pc.b2 = b2; pc.b3 = b3;
    pc.h1seq = h1seq; pc.h2seq = h2seq;
    pc.h1a = h1a; pc.h1b = h1b; pc.h2a = h2a; pc.h2b = h2b;
    pc.h3a = h3a; pc.h3b = h3b;
    pc.c1s = c1s; pc.c2s = c2s; pc.c3s = c3s;
    pc.h3bn = h3bn;
    pc.g1 = g1; pc.be1 = be1; pc.m1 = m1; pc.v1 = v1;
    pc.g2 = g2; pc.be2 = be2; pc.m2 = m2; pc.v2 = v2;
    pc.g3 = g3; pc.be3 = be3; pc.m3 = m3; pc.v3 = v3;
    pc.T = T; pc.L = L;
    convlstm_persist<<<768, 256, 0, stream>>>(pc, bar);

    // ---- dense head ----
    {
        const int K = L * F3;              // 32768
        dense_partial<<<dim3(8, 128), 256, 0, stream>>>(h3bn, D1, partials, K, 1024);
        dense_reduce_relu<<<(B * 1024) / 256, 256, 0, stream>>>(partials, db1, a1, 1024, 128);
    }
    dense_relu<<<dim3(512 / 256, B), 256, 0, stream>>>(a1, D2, db2, a2, 1024, 512);
    dense_softmax<<<B, 64, 0, stream>>>(a2, D3, db3, (float*)d_out);
}